// Round 11
// baseline (1916.642 us; speedup 1.0000x reference)
//
#include <hip/hip_runtime.h>
#include <hip/hip_bf16.h>

#define NN 50000
#define EE 1600000
#define FF 384
#define MPAD 50048
#define NITER 5
#define EPB 6250      // edges per block in bucket_scatter
#define BCAP 220000   // bucket capacity (mean 200000, +47 sigma)
#define GRP 6250      // rows per dst-group (NN/8)
#define RPB 16        // rows per block in spmm
#define RBLK 3125     // row-blocks per pass (NN/RPB)
#define NPASS 12      // feature passes (16 u32 cols each)

typedef unsigned int u32;
typedef unsigned short u16;
typedef __attribute__((ext_vector_type(8))) short short8;
typedef __attribute__((ext_vector_type(4))) float f32x4;

typedef const __attribute__((address_space(1))) void* gptr_t;
typedef __attribute__((address_space(3))) void* lptr_t;

__device__ __forceinline__ float bf_lo(u32 u) {
  u32 v = u << 16;
  return __builtin_bit_cast(float, v);
}
__device__ __forceinline__ float bf_hi(u32 u) {
  u32 v = u & 0xFFFF0000u;
  return __builtin_bit_cast(float, v);
}
__device__ __forceinline__ u32 f2bf(float f) {  // RNE f32 -> bf16 bits
  u32 u = __builtin_bit_cast(u32, f);
  return (u + 0x7FFFu + ((u >> 16) & 1u)) >> 16;
}
__device__ __forceinline__ u32 pack2(float lo, float hi) {
  return f2bf(lo) | (f2bf(hi) << 16);
}
__device__ __forceinline__ void load16_lds(const void* g, void* l) {
  __builtin_amdgcn_global_load_lds((gptr_t)g, (lptr_t)l, 16, 0, 0);
}

// ---------------- setup ----------------
__global__ void init_bcur_kernel(int* __restrict__ bcur) {
  if (threadIdx.x < 8) bcur[threadIdx.x] = threadIdx.x * BCAP;
}

// Pass A: block-local LDS counting sort of 6250 edges into 8 dst-range buckets,
// then fully COALESCED copy-out to reserved global bucket ranges.
__global__ __launch_bounds__(256) void bucket_scatter_kernel(
    const int* __restrict__ src, const int* __restrict__ dst,
    int* __restrict__ bcur, int* __restrict__ es_src, int* __restrict__ es_dst) {
  __shared__ int osrc[EPB];
  __shared__ int odst[EPB];
  __shared__ int h[8], lo8[8], gbase[8], c2[8];
  const int t = threadIdx.x;
  if (t < 8) { h[t] = 0; c2[t] = 0; }
  __syncthreads();
  const int e0 = blockIdx.x * EPB;
  for (int i = t; i < EPB; i += 256) {
    int d = dst[e0 + i];
    atomicAdd(&h[d / GRP], 1);
  }
  __syncthreads();
  if (t == 0) { int r = 0; for (int b = 0; b < 8; ++b) { lo8[b] = r; r += h[b]; } }
  __syncthreads();
  if (t < 8) gbase[t] = atomicAdd(&bcur[t], h[t]);
  __syncthreads();
  for (int i = t; i < EPB; i += 256) {
    int s = src[e0 + i], d = dst[e0 + i];
    int b = d / GRP;
    int p = lo8[b] + atomicAdd(&c2[b], 1);
    osrc[p] = s; odst[p] = d;
  }
  __syncthreads();
  for (int i = t; i < EPB; i += 256) {
    int b = 0;
    while (b < 7 && i >= lo8[b + 1]) ++b;
    int g = gbase[b] + (i - lo8[b]);
    es_src[g] = osrc[i];
    es_dst[g] = odst[i];
  }
}

// Per-group LDS histogram: ZERO global atomics. One block per group, 512 thr.
__global__ __launch_bounds__(512) void hist2_kernel(
    const int* __restrict__ es_dst, const int* __restrict__ bcur,
    int* __restrict__ cnt) {
  __shared__ int h[GRP];
  const int g = blockIdx.x;
  const int lo = g * GRP;
  const int base = g * BCAP;
  const int n = bcur[g] - base;
  for (int i = threadIdx.x; i < GRP; i += 512) h[i] = 0;
  __syncthreads();
  for (int i = threadIdx.x; i < n; i += 512)
    atomicAdd(&h[es_dst[base + i] - lo], 1);
  __syncthreads();
  for (int i = threadIdx.x; i < GRP; i += 512) cnt[lo + i] = h[i];
}

// 256 threads, each owns 196 rows; vectorized sums + shuffle scan
__global__ void scan_kernel(const int* __restrict__ cnt, int* __restrict__ row_start) {
  __shared__ int wsum[4];
  const int CH = 196;  // 255*196=49980 < 50000 <= 256*196
  int t = threadIdx.x;
  int lo = t * CH;
  int hi = lo + CH; if (hi > NN) hi = NN;  // t=255 -> [49980,50000), len 20 (%4==0)
  int s = 0;
  int n4 = (hi - lo) >> 2;
  const int4* p = (const int4*)(cnt + lo);
  for (int i = 0; i < n4; ++i) { int4 c = p[i]; s += c.x + c.y + c.z + c.w; }
  int lane = t & 63, w = t >> 6;
  int v = s;
  for (int d = 1; d < 64; d <<= 1) { int u = __shfl_up(v, d, 64); if (lane >= d) v += u; }
  if (lane == 63) wsum[w] = v;
  __syncthreads();
  int run = v - s;  // exclusive within wave
  for (int i = 0; i < w; ++i) run += wsum[i];
  int4* q1 = (int4*)(row_start + lo);
  for (int k = 0; k < n4; ++k) {
    int4 c = p[k];
    int4 o; o.x = run; o.y = run + c.x; o.z = o.y + c.y; o.w = o.z + c.z;
    run = o.w + c.w;
    q1[k] = o;
  }
  if (hi == NN && lo < NN) row_start[NN] = run;  // t=255: run == EE
}

// Final scatter with LDS cursors: ZERO global atomics. One block per group ->
// col writes span one contiguous ~800KB range from ONE CU/XCD -> L2-merged.
__global__ __launch_bounds__(512) void scatter2_kernel(
    const int* __restrict__ es_src, const int* __restrict__ es_dst,
    const int* __restrict__ bcur, const int* __restrict__ row_start,
    int* __restrict__ col) {
  __shared__ int cur[GRP];
  const int g = blockIdx.x;
  const int lo = g * GRP;
  const int base = g * BCAP;
  const int n = bcur[g] - base;
  for (int i = threadIdx.x; i < GRP; i += 512) cur[i] = row_start[lo + i];
  __syncthreads();
  for (int i = threadIdx.x; i < n; i += 512) {
    int d = es_dst[base + i];
    int s = es_src[base + i];
    int p = atomicAdd(&cur[d - lo], 1);
    col[p] = s;
  }
}

// ---------------- converts ----------------
__global__ void convert_x_kernel(const float* __restrict__ xin, u16* __restrict__ xout) {
  size_t i = ((size_t)blockIdx.x * 256 + threadIdx.x) * 4;
  if (i >= (size_t)NN * FF) return;
  float4 f = *(const float4*)(xin + i);
  u32 o0 = pack2(f.x, f.y);
  u32 o1 = pack2(f.z, f.w);
  u32* q = (u32*)(xout + i);
  q[0] = o0; q[1] = o1;
}

// Bt[n][k] (384 x 768 bf16, row-major): k<384 -> W_rel[n][k], else W_root[n][k-384]
__global__ void build_bt_kernel(const float* __restrict__ Wr, const float* __restrict__ Wt,
                                u16* __restrict__ Bt) {
  int i = blockIdx.x * 256 + threadIdx.x;  // i = n*768 + k
  if (i >= FF * 2 * FF) return;
  int n = i / (2 * FF);
  int k = i - n * (2 * FF);
  float v = (k < FF) ? Wr[n * FF + k] : Wt[n * FF + (k - FF)];
  Bt[i] = (u16)f2bf(v);
}

// ---------------- SpMM: agg[dst] = sum_src x[src], 12 L2-resident slices ----------------
// ONE launch: pass = blockIdx/3125 (pass-major dispatch). Each pass covers 16 u32
// columns = 3.2MB slice of x (< 4MB per-XCD L2) -> gather re-reads are L2 hits.
// Per edge: exactly one 64B line (16 lanes x 4B). col via NT loads + width-16
// shuffle broadcast (no L2 pollution); agg via NT stores. 4 rows/wave.
__global__ __launch_bounds__(256) void spmm12_kernel(
    const u16* __restrict__ x, const int* __restrict__ rs,
    const int* __restrict__ col, u16* __restrict__ agg) {
  const int pass = blockIdx.x / RBLK;
  const int rb = blockIdx.x - pass * RBLK;
  const int lane = threadIdx.x & 63;
  const int sl = lane & 15;
  const int r = rb * RPB + (threadIdx.x >> 6) * 4 + (lane >> 4);  // < 50000 always
  const int fo = pass * 16;

  const int j0 = rs[r], j1 = rs[r + 1];
  const u32* xw = (const u32*)x + fo + sl;
  float alo = 0.f, ahi = 0.f;

  int j = j0;
  for (; j + 16 <= j1; j += 16) {
    int colv = __builtin_nontemporal_load(col + j + sl);
#pragma unroll
    for (int k = 0; k < 16; ++k) {
      int s = __shfl(colv, k, 16);
      u32 u = xw[(size_t)s * 192];
      alo += bf_lo(u); ahi += bf_hi(u);
    }
  }
  if (j < j1) {
    int idx = j + sl; if (idx >= j1) idx = j1 - 1;
    int colv = __builtin_nontemporal_load(col + idx);
    int n = j1 - j;
    for (int k = 0; k < n; ++k) {
      int s = __shfl(colv, k, 16);
      u32 u = xw[(size_t)s * 192];
      alo += bf_lo(u); ahi += bf_hi(u);
    }
  }
  __builtin_nontemporal_store(pack2(alo, ahi), (u32*)agg + (size_t)r * 192 + fo + sl);
}

// ---------------- GEMM: Xout = relu([agg | x] @ Bt^T) ----------------
// bf16 in/out, fp32 accum. BM=64, BN=384 (full N -> A staged ONCE).
// 512 threads = 8 waves (2m x 4n), wave tile 32x96, acc[2][6] = 48 VGPR.
// A: LDS dbuf 2x8KB; B: LDS single 48KB (coalesced global_load_lds w16,
// XOR swizzle both). grid = 782 blocks, bijective XCD swizzle.
__global__ __launch_bounds__(512, 4) void gemm_kernel(
    const u16* __restrict__ Aagg, const u16* __restrict__ Ax,
    const u16* __restrict__ Bt, u16* __restrict__ Xout) {
  __shared__ __align__(16) u16 As[2][64 * 64];
  __shared__ __align__(16) u16 Bs[384 * 64];

  // bijective XCD swizzle: nwg=782, q=97, r=6
  const int orig = blockIdx.x;
  const int xcd = orig & 7, idx = orig >> 3;
  const int wg = ((xcd < 6) ? xcd * 98 : 6 * 98 + (xcd - 6) * 97) + idx;
  const int m0 = wg * 64;

  const int tid = threadIdx.x;
  const int lane = tid & 63;
  const int w = tid >> 6;        // 0..7
  const int wr = w >> 2;         // 0..1  (32-row half)
  const int wc = w & 3;          // 0..3  (96-col group)

  f32x4 acc[2][6] = {};

#define STAGE_A(KT, BUF)                                                        \
  {                                                                             \
    const u16* Asrc_ = ((KT) < 6) ? Aagg : Ax;                                  \
    const int kbA_ = (((KT) < 6) ? (KT) : (KT)-6) << 7;                         \
    const int rA_ = tid >> 3;                                                   \
    const int bcA_ = (tid & 7) << 4;                                            \
    load16_lds((const char*)Asrc_ + (size_t)(m0 + rA_) * 768 + kbA_ +           \
                   (bcA_ ^ ((rA_ & 7) << 4)),                                   \
               (char*)&As[BUF][0] + tid * 16);                                  \
  }

#define STAGE_B(KT)                                                             \
  {                                                                             \
    const int kbB_ = (KT) << 7;                                                 \
    _Pragma("unroll")                                                           \
    for (int i = 0; i < 6; ++i) {                                               \
      const int c = tid + i * 512;                                              \
      const int rB_ = c >> 3;                                                   \
      const int bcB_ = (c & 7) << 4;                                            \
      load16_lds((const char*)Bt + (size_t)rB_ * 1536 + kbB_ +                  \
                     (bcB_ ^ ((rB_ & 7) << 4)),                                 \
                 (char*)&Bs[0] + c * 16);                                       \
    }                                                                           \
  }

  STAGE_A(0, 0);
  STAGE_B(0);
  __syncthreads();

  int buf = 0;
  for (int kt = 0; kt < 12; ++kt) {
    if (kt < 11) STAGE_A(kt + 1, buf ^ 1);  // A prefetch overlaps compute
#pragma unroll
    for (int ks = 0; ks < 2; ++ks) {
      short8 af[2], bfm[6];
#pragma unroll
      for (int ni = 0; ni < 6; ++ni) {
        const int r = wc * 96 + ni * 16 + (lane & 15);
        const int bc = (ks * 64 + ((lane >> 4) << 4)) ^ ((r & 7) << 4);
        bfm[ni] = *(const short8*)((const char*)&Bs[0] + r * 128 + bc);
      }
#pragma unroll
      for (int mi = 0; mi < 2; ++mi) {
        const int r = wr * 32 + mi * 16 + (lane & 15);
        const int bc = (ks * 64 + ((lane >> 4) << 4)) ^ ((r & 7) << 4);
        af[mi] = *(const short8*)((const char*)&As[buf][0] + r * 128 + bc);
      }
#pragma unroll
      for (int mi = 0; mi < 2; ++mi)
#pragma unroll
        for (int ni = 0; ni < 6; ++ni)
          acc[mi][ni] = __builtin_amdgcn_mfma_f32_16x16x32_bf16(af[mi], bfm[ni], acc[mi][ni], 0, 0, 0);
    }
    __syncthreads();  // all waves done reading Bs + As[buf]; drains A prefetch
    if (kt < 11) {
      STAGE_B(kt + 1);
      __syncthreads();  // B(kt+1) ready (sibling block hides this drain)
    }
    buf ^= 1;
  }

  // epilogue: relu -> bf16. D layout: col = lane&15, row = (lane>>4)*4 + reg (m89-verified)
#pragma unroll
  for (int mi = 0; mi < 2; ++mi) {
#pragma unroll
    for (int r = 0; r < 4; ++r) {
      const int row = m0 + wr * 32 + mi * 16 + ((lane >> 4) << 2) + r;
      u16* orow = Xout + (size_t)row * FF + wc * 96 + (lane & 15);
#pragma unroll
      for (int ni = 0; ni < 6; ++ni) {
        float v = fmaxf(acc[mi][ni][r], 0.0f);
        orow[ni * 16] = (u16)f2bf(v);
      }
    }
  }
#undef STAGE_A
#undef STAGE_B
}

// ---------------- readout: out[n] = dot(x[n,:], W_lin) ----------------
__global__ void readout_kernel(const u16* __restrict__ x, const float* __restrict__ wl,
                               float* __restrict__ out) {
  int row = blockIdx.x * 4 + (threadIdx.x >> 6);
  int lane = threadIdx.x & 63;
  if (row >= NN) return;
  const u32* p = (const u32*)(x + (size_t)row * FF) + lane * 3;
  u32 u0 = p[0], u1 = p[1], u2 = p[2];
  const float* w = wl + lane * 6;
  float s = bf_lo(u0) * w[0] + bf_hi(u0) * w[1] +
            bf_lo(u1) * w[2] + bf_hi(u1) * w[3] +
            bf_lo(u2) * w[4] + bf_hi(u2) * w[5];
#pragma unroll
  for (int off = 32; off > 0; off >>= 1) s += __shfl_down(s, off, 64);
  if (lane == 0) out[row] = s;
}

extern "C" void kernel_launch(void* const* d_in, const int* in_sizes, int n_in,
                              void* d_out, int out_size, void* d_ws, size_t ws_size,
                              hipStream_t stream) {
  const float* x_in = (const float*)d_in[0];
  const int* ei = (const int*)d_in[1];
  const float* W_rel = (const float*)d_in[3];
  const float* W_root = (const float*)d_in[4];
  const float* W_lin = (const float*)d_in[5];
  float* out = (float*)d_out;

  char* ws = (char*)d_ws;
  int* cnt = (int*)(ws);                      // 200,000 B used (+64 spare)
  int* bcur = cnt + NN;                       // 8 ints in the spare
  int* row_start = (int*)(ws + 200064);       // 200,064 B
  int* col = (int*)(ws + 600192);             // 6,400,000 B
  u16* Bt = (u16*)(ws + 7000192);             // 589,824 B
  u16* agg = (u16*)(ws + 7590016);            // 38,436,864 B
  u16* x0 = (u16*)(ws + 46026880);            // 38,436,864 B
  u16* x1 = (u16*)(ws + 84463744);            // 38,436,864 B
  if (ws_size < (size_t)122900608) return;    // need ~117 MB
  // transient bucket arrays overlay agg (dead before first spmm write)
  int* es_src = (int*)(ws + 7590016);                 // 7,040,000 B
  int* es_dst = (int*)(ws + 7590016 + 7040000);       // 7,040,000 B

  const int* esrc = ei;
  const int* edst = ei + EE;

  // zero pad rows once per launch (GEMM reads them; pad outputs are row-local)
  hipMemsetAsync(agg + (size_t)NN * FF, 0, (size_t)(MPAD - NN) * FF * sizeof(u16), stream);
  hipMemsetAsync(x0 + (size_t)NN * FF, 0, (size_t)(MPAD - NN) * FF * sizeof(u16), stream);
  hipMemsetAsync(x1 + (size_t)NN * FF, 0, (size_t)(MPAD - NN) * FF * sizeof(u16), stream);

  init_bcur_kernel<<<1, 64, 0, stream>>>(bcur);
  bucket_scatter_kernel<<<EE / EPB, 256, 0, stream>>>(esrc, edst, bcur, es_src, es_dst);
  hist2_kernel<<<8, 512, 0, stream>>>(es_dst, bcur, cnt);
  scan_kernel<<<1, 256, 0, stream>>>(cnt, row_start);
  scatter2_kernel<<<8, 512, 0, stream>>>(es_src, es_dst, bcur, row_start, col);
  convert_x_kernel<<<(NN * FF / 4 + 255) / 256, 256, 0, stream>>>(x_in, x0);
  build_bt_kernel<<<(FF * 2 * FF + 255) / 256, 256, 0, stream>>>(W_rel, W_root, Bt);

  u16* xs = x0;
  u16* xd = x1;
  for (int t = 0; t < NITER; ++t) {
    spmm12_kernel<<<NPASS * RBLK, 256, 0, stream>>>(xs, row_start, col, agg);
    gemm_kernel<<<MPAD / 64, 512, 0, stream>>>(agg, xs, Bt, xd);
    u16* tmp = xs; xs = xd; xd = tmp;
  }
  readout_kernel<<<NN / 4, 256, 0, stream>>>(xs, W_lin, out);
}

// Round 12
// 1238.435 us; speedup vs baseline: 1.5476x; 1.5476x over previous
//
#include <hip/hip_runtime.h>
#include <hip/hip_bf16.h>

#define NN 50000
#define EE 1600000
#define FF 384
#define MPAD 50048
#define NITER 5
#define EPB 6250      // edges per block in bucket_scatter
#define BCAP 220000   // bucket capacity (mean 200000, +47 sigma)
#define GRP 6250      // rows per dst-group (NN/8)

typedef unsigned int u32;
typedef unsigned short u16;
typedef __attribute__((ext_vector_type(8))) short short8;
typedef __attribute__((ext_vector_type(4))) float f32x4;

typedef const __attribute__((address_space(1))) void* gptr_t;
typedef __attribute__((address_space(3))) void* lptr_t;

__device__ __forceinline__ float bf_lo(u32 u) {
  u32 v = u << 16;
  return __builtin_bit_cast(float, v);
}
__device__ __forceinline__ float bf_hi(u32 u) {
  u32 v = u & 0xFFFF0000u;
  return __builtin_bit_cast(float, v);
}
__device__ __forceinline__ u32 f2bf(float f) {  // RNE f32 -> bf16 bits
  u32 u = __builtin_bit_cast(u32, f);
  return (u + 0x7FFFu + ((u >> 16) & 1u)) >> 16;
}
__device__ __forceinline__ u32 pack2(float lo, float hi) {
  return f2bf(lo) | (f2bf(hi) << 16);
}
__device__ __forceinline__ void load16_lds(const void* g, void* l) {
  __builtin_amdgcn_global_load_lds((gptr_t)g, (lptr_t)l, 16, 0, 0);
}

// ---------------- setup ----------------
__global__ void init_bcur_kernel(int* __restrict__ bcur) {
  if (threadIdx.x < 8) bcur[threadIdx.x] = threadIdx.x * BCAP;
}

// Pass A: block-local LDS counting sort of 6250 edges into 8 dst-range buckets,
// then fully COALESCED copy-out to reserved global bucket ranges.
__global__ __launch_bounds__(256) void bucket_scatter_kernel(
    const int* __restrict__ src, const int* __restrict__ dst,
    int* __restrict__ bcur, int* __restrict__ es_src, int* __restrict__ es_dst) {
  __shared__ int osrc[EPB];
  __shared__ int odst[EPB];
  __shared__ int h[8], lo8[8], gbase[8], c2[8];
  const int t = threadIdx.x;
  if (t < 8) { h[t] = 0; c2[t] = 0; }
  __syncthreads();
  const int e0 = blockIdx.x * EPB;
  for (int i = t; i < EPB; i += 256) {
    int d = dst[e0 + i];
    atomicAdd(&h[d / GRP], 1);
  }
  __syncthreads();
  if (t == 0) { int r = 0; for (int b = 0; b < 8; ++b) { lo8[b] = r; r += h[b]; } }
  __syncthreads();
  if (t < 8) gbase[t] = atomicAdd(&bcur[t], h[t]);
  __syncthreads();
  for (int i = t; i < EPB; i += 256) {
    int s = src[e0 + i], d = dst[e0 + i];
    int b = d / GRP;
    int p = lo8[b] + atomicAdd(&c2[b], 1);
    osrc[p] = s; odst[p] = d;
  }
  __syncthreads();
  for (int i = t; i < EPB; i += 256) {
    int b = 0;
    while (b < 7 && i >= lo8[b + 1]) ++b;
    int g = gbase[b] + (i - lo8[b]);
    es_src[g] = osrc[i];
    es_dst[g] = odst[i];
  }
}

// XCD-affine hist: group g = blockIdx&7 -> (round-robin) all 32 of group g's
// blocks land on XCD g; its random atomics hit a 25KB cnt region owned by ONE
// XCD -> lines stay in that L2, no cross-XCD write-through.
__global__ __launch_bounds__(256) void hist3_kernel(
    const int* __restrict__ es_dst, const int* __restrict__ bcur,
    int* __restrict__ cnt) {
  const int g = blockIdx.x & 7;
  const int sub = blockIdx.x >> 3;  // 0..31
  const int base = g * BCAP;
  const int n = bcur[g] - base;
  const int chunk = (n + 31) >> 5;
  const int i0 = sub * chunk;
  int i1 = i0 + chunk; if (i1 > n) i1 = n;
  for (int i = i0 + threadIdx.x; i < i1; i += 256)
    atomicAdd(&cnt[es_dst[base + i]], 1);
}

// 256 threads, each owns 196 rows; vectorized sums + shuffle scan
__global__ void scan_kernel(const int* __restrict__ cnt, int* __restrict__ row_start,
                            int* __restrict__ cursor) {
  __shared__ int wsum[4];
  const int CH = 196;  // 255*196=49980 < 50000 <= 256*196
  int t = threadIdx.x;
  int lo = t * CH;
  int hi = lo + CH; if (hi > NN) hi = NN;  // t=255 -> [49980,50000), len 20 (%4==0)
  int s = 0;
  int n4 = (hi - lo) >> 2;
  const int4* p = (const int4*)(cnt + lo);
  for (int i = 0; i < n4; ++i) { int4 c = p[i]; s += c.x + c.y + c.z + c.w; }
  int lane = t & 63, w = t >> 6;
  int v = s;
  for (int d = 1; d < 64; d <<= 1) { int u = __shfl_up(v, d, 64); if (lane >= d) v += u; }
  if (lane == 63) wsum[w] = v;
  __syncthreads();
  int run = v - s;  // exclusive within wave
  for (int i = 0; i < w; ++i) run += wsum[i];
  int4* q1 = (int4*)(row_start + lo);
  int4* q2 = (int4*)(cursor + lo);
  for (int k = 0; k < n4; ++k) {
    int4 c = p[k];
    int4 o; o.x = run; o.y = run + c.x; o.z = o.y + c.y; o.w = o.z + c.z;
    run = o.w + c.w;
    q1[k] = o; q2[k] = o;
  }
  if (hi == NN && lo < NN) row_start[NN] = run;  // t=255: run == EE
}

// XCD-affine scatter: group g's cursor region (25KB) + col range (~800KB) are
// touched ONLY by XCD g's blocks -> atomics and writes merge in its L2.
__global__ __launch_bounds__(256) void scatter3_kernel(
    const int* __restrict__ es_src, const int* __restrict__ es_dst,
    const int* __restrict__ bcur, int* __restrict__ cursor, int* __restrict__ col) {
  const int g = blockIdx.x & 7;
  const int sub = blockIdx.x >> 3;  // 0..31
  const int base = g * BCAP;
  const int n = bcur[g] - base;
  const int chunk = (n + 31) >> 5;
  const int i0 = sub * chunk;
  int i1 = i0 + chunk; if (i1 > n) i1 = n;
  for (int i = i0 + threadIdx.x; i < i1; i += 256) {
    int d = es_dst[base + i];
    int s = es_src[base + i];
    int p = atomicAdd(&cursor[d], 1);
    col[p] = s;
  }
}

// ---------------- converts ----------------
__global__ void convert_x_kernel(const float* __restrict__ xin, u16* __restrict__ xout) {
  size_t i = ((size_t)blockIdx.x * 256 + threadIdx.x) * 4;
  if (i >= (size_t)NN * FF) return;
  float4 f = *(const float4*)(xin + i);
  u32 o0 = pack2(f.x, f.y);
  u32 o1 = pack2(f.z, f.w);
  u32* q = (u32*)(xout + i);
  q[0] = o0; q[1] = o1;
}

// Bt[n][k] (384 x 768 bf16, row-major): k<384 -> W_rel[n][k], else W_root[n][k-384]
__global__ void build_bt_kernel(const float* __restrict__ Wr, const float* __restrict__ Wt,
                                u16* __restrict__ Bt) {
  int i = blockIdx.x * 256 + threadIdx.x;  // i = n*768 + k
  if (i >= FF * 2 * FF) return;
  int n = i / (2 * FF);
  int k = i - n * (2 * FF);
  float v = (k < FF) ? Wr[n * FF + k] : Wt[n * FF + (k - FF)];
  Bt[i] = (u16)f2bf(v);
}

// ---------------- SpMM: agg[dst] = sum_src x[src], feature-split x3 (r8 best) ----------------
__global__ void spmm_pass_kernel(const u16* __restrict__ x, const int* __restrict__ rs,
                                 const int* __restrict__ col, u16* __restrict__ agg,
                                 const int fo) {
  int row = blockIdx.x * 4 + (threadIdx.x >> 6);
  int lane = threadIdx.x & 63;
  if (row >= NN) return;
  int j0 = rs[row], j1 = rs[row + 1];
  float alo = 0.f, ahi = 0.f;
  const u32* xw = (const u32*)x + fo + lane;
  int j = j0;
  for (; j + 8 <= j1; j += 8) {
    int s0 = col[j + 0], s1 = col[j + 1], s2 = col[j + 2], s3 = col[j + 3];
    int s4 = col[j + 4], s5 = col[j + 5], s6 = col[j + 6], s7 = col[j + 7];
    u32 u0 = xw[(size_t)s0 * 192];
    u32 u1 = xw[(size_t)s1 * 192];
    u32 u2 = xw[(size_t)s2 * 192];
    u32 u3 = xw[(size_t)s3 * 192];
    u32 u4 = xw[(size_t)s4 * 192];
    u32 u5 = xw[(size_t)s5 * 192];
    u32 u6 = xw[(size_t)s6 * 192];
    u32 u7 = xw[(size_t)s7 * 192];
    alo += bf_lo(u0) + bf_lo(u1) + bf_lo(u2) + bf_lo(u3) +
           bf_lo(u4) + bf_lo(u5) + bf_lo(u6) + bf_lo(u7);
    ahi += bf_hi(u0) + bf_hi(u1) + bf_hi(u2) + bf_hi(u3) +
           bf_hi(u4) + bf_hi(u5) + bf_hi(u6) + bf_hi(u7);
  }
  for (; j < j1; ++j) {
    u32 u = xw[(size_t)col[j] * 192];
    alo += bf_lo(u); ahi += bf_hi(u);
  }
  ((u32*)agg)[(size_t)row * 192 + fo + lane] = pack2(alo, ahi);
}

// ---------------- GEMM: Xout = relu([agg | x] @ Bt^T) ----------------
// bf16 in/out, fp32 accum. BM=64, BN=384 (full N -> A staged ONCE).
// 512 threads = 8 waves (2m x 4n), wave tile 32x96, acc[2][6] = 48 VGPR.
// A: LDS dbuf 2x8KB; B: LDS single 48KB (coalesced global_load_lds w16,
// XOR swizzle both). grid = 782 blocks, bijective XCD swizzle.
__global__ __launch_bounds__(512, 4) void gemm_kernel(
    const u16* __restrict__ Aagg, const u16* __restrict__ Ax,
    const u16* __restrict__ Bt, u16* __restrict__ Xout) {
  __shared__ __align__(16) u16 As[2][64 * 64];
  __shared__ __align__(16) u16 Bs[384 * 64];

  // bijective XCD swizzle: nwg=782, q=97, r=6
  const int orig = blockIdx.x;
  const int xcd = orig & 7, idx = orig >> 3;
  const int wg = ((xcd < 6) ? xcd * 98 : 6 * 98 + (xcd - 6) * 97) + idx;
  const int m0 = wg * 64;

  const int tid = threadIdx.x;
  const int lane = tid & 63;
  const int w = tid >> 6;        // 0..7
  const int wr = w >> 2;         // 0..1  (32-row half)
  const int wc = w & 3;          // 0..3  (96-col group)

  f32x4 acc[2][6] = {};

#define STAGE_A(KT, BUF)                                                        \
  {                                                                             \
    const u16* Asrc_ = ((KT) < 6) ? Aagg : Ax;                                  \
    const int kbA_ = (((KT) < 6) ? (KT) : (KT)-6) << 7;                         \
    const int rA_ = tid >> 3;                                                   \
    const int bcA_ = (tid & 7) << 4;                                            \
    load16_lds((const char*)Asrc_ + (size_t)(m0 + rA_) * 768 + kbA_ +           \
                   (bcA_ ^ ((rA_ & 7) << 4)),                                   \
               (char*)&As[BUF][0] + tid * 16);                                  \
  }

#define STAGE_B(KT)                                                             \
  {                                                                             \
    const int kbB_ = (KT) << 7;                                                 \
    _Pragma("unroll")                                                           \
    for (int i = 0; i < 6; ++i) {                                               \
      const int c = tid + i * 512;                                              \
      const int rB_ = c >> 3;                                                   \
      const int bcB_ = (c & 7) << 4;                                            \
      load16_lds((const char*)Bt + (size_t)rB_ * 1536 + kbB_ +                  \
                     (bcB_ ^ ((rB_ & 7) << 4)),                                 \
                 (char*)&Bs[0] + c * 16);                                       \
    }                                                                           \
  }

  STAGE_A(0, 0);
  STAGE_B(0);
  __syncthreads();

  int buf = 0;
  for (int kt = 0; kt < 12; ++kt) {
    if (kt < 11) STAGE_A(kt + 1, buf ^ 1);  // A prefetch overlaps compute
#pragma unroll
    for (int ks = 0; ks < 2; ++ks) {
      short8 af[2], bfm[6];
#pragma unroll
      for (int ni = 0; ni < 6; ++ni) {
        const int r = wc * 96 + ni * 16 + (lane & 15);
        const int bc = (ks * 64 + ((lane >> 4) << 4)) ^ ((r & 7) << 4);
        bfm[ni] = *(const short8*)((const char*)&Bs[0] + r * 128 + bc);
      }
#pragma unroll
      for (int mi = 0; mi < 2; ++mi) {
        const int r = wr * 32 + mi * 16 + (lane & 15);
        const int bc = (ks * 64 + ((lane >> 4) << 4)) ^ ((r & 7) << 4);
        af[mi] = *(const short8*)((const char*)&As[buf][0] + r * 128 + bc);
      }
#pragma unroll
      for (int mi = 0; mi < 2; ++mi)
#pragma unroll
        for (int ni = 0; ni < 6; ++ni)
          acc[mi][ni] = __builtin_amdgcn_mfma_f32_16x16x32_bf16(af[mi], bfm[ni], acc[mi][ni], 0, 0, 0);
    }
    __syncthreads();  // all waves done reading Bs + As[buf]; drains A prefetch
    if (kt < 11) {
      STAGE_B(kt + 1);
      __syncthreads();  // B(kt+1) ready (sibling block hides this drain)
    }
    buf ^= 1;
  }

  // epilogue: relu -> bf16. D layout: col = lane&15, row = (lane>>4)*4 + reg (m89-verified)
#pragma unroll
  for (int mi = 0; mi < 2; ++mi) {
#pragma unroll
    for (int r = 0; r < 4; ++r) {
      const int row = m0 + wr * 32 + mi * 16 + ((lane >> 4) << 2) + r;
      u16* orow = Xout + (size_t)row * FF + wc * 96 + (lane & 15);
#pragma unroll
      for (int ni = 0; ni < 6; ++ni) {
        float v = fmaxf(acc[mi][ni][r], 0.0f);
        orow[ni * 16] = (u16)f2bf(v);
      }
    }
  }
#undef STAGE_A
#undef STAGE_B
}

// ---------------- readout: out[n] = dot(x[n,:], W_lin) ----------------
__global__ void readout_kernel(const u16* __restrict__ x, const float* __restrict__ wl,
                               float* __restrict__ out) {
  int row = blockIdx.x * 4 + (threadIdx.x >> 6);
  int lane = threadIdx.x & 63;
  if (row >= NN) return;
  const u32* p = (const u32*)(x + (size_t)row * FF) + lane * 3;
  u32 u0 = p[0], u1 = p[1], u2 = p[2];
  const float* w = wl + lane * 6;
  float s = bf_lo(u0) * w[0] + bf_hi(u0) * w[1] +
            bf_lo(u1) * w[2] + bf_hi(u1) * w[3] +
            bf_lo(u2) * w[4] + bf_hi(u2) * w[5];
#pragma unroll
  for (int off = 32; off > 0; off >>= 1) s += __shfl_down(s, off, 64);
  if (lane == 0) out[row] = s;
}

extern "C" void kernel_launch(void* const* d_in, const int* in_sizes, int n_in,
                              void* d_out, int out_size, void* d_ws, size_t ws_size,
                              hipStream_t stream) {
  const float* x_in = (const float*)d_in[0];
  const int* ei = (const int*)d_in[1];
  const float* W_rel = (const float*)d_in[3];
  const float* W_root = (const float*)d_in[4];
  const float* W_lin = (const float*)d_in[5];
  float* out = (float*)d_out;

  char* ws = (char*)d_ws;
  int* cnt = (int*)(ws);                      // 200,000 B used (+64 spare)
  int* bcur = cnt + NN;                       // 8 ints in the spare
  int* row_start = (int*)(ws + 200064);       // 200,064 B
  int* cursor = (int*)(ws + 400128);          // 200,064 B
  int* col = (int*)(ws + 600192);             // 6,400,000 B
  u16* Bt = (u16*)(ws + 7000192);             // 589,824 B
  u16* agg = (u16*)(ws + 7590016);            // 38,436,864 B
  u16* x0 = (u16*)(ws + 46026880);            // 38,436,864 B
  u16* x1 = (u16*)(ws + 84463744);            // 38,436,864 B
  if (ws_size < (size_t)122900608) return;    // need ~117 MB
  // transient bucket arrays overlay agg (dead before first spmm write)
  int* es_src = (int*)(ws + 7590016);                 // 7,040,000 B
  int* es_dst = (int*)(ws + 7590016 + 7040000);       // 7,040,000 B

  const int* esrc = ei;
  const int* edst = ei + EE;

  hipMemsetAsync(cnt, 0, NN * sizeof(int), stream);
  // zero pad rows once per launch (GEMM reads them; pad outputs are row-local)
  hipMemsetAsync(agg + (size_t)NN * FF, 0, (size_t)(MPAD - NN) * FF * sizeof(u16), stream);
  hipMemsetAsync(x0 + (size_t)NN * FF, 0, (size_t)(MPAD - NN) * FF * sizeof(u16), stream);
  hipMemsetAsync(x1 + (size_t)NN * FF, 0, (size_t)(MPAD - NN) * FF * sizeof(u16), stream);

  init_bcur_kernel<<<1, 64, 0, stream>>>(bcur);
  bucket_scatter_kernel<<<EE / EPB, 256, 0, stream>>>(esrc, edst, bcur, es_src, es_dst);
  hist3_kernel<<<256, 256, 0, stream>>>(es_dst, bcur, cnt);
  scan_kernel<<<1, 256, 0, stream>>>(cnt, row_start, cursor);
  scatter3_kernel<<<256, 256, 0, stream>>>(es_src, es_dst, bcur, cursor, col);
  convert_x_kernel<<<(NN * FF / 4 + 255) / 256, 256, 0, stream>>>(x_in, x0);
  build_bt_kernel<<<(FF * 2 * FF + 255) / 256, 256, 0, stream>>>(W_rel, W_root, Bt);

  u16* xs = x0;
  u16* xd = x1;
  for (int t = 0; t < NITER; ++t) {
    for (int p = 0; p < 3; ++p)
      spmm_pass_kernel<<<NN / 4, 256, 0, stream>>>(xs, row_start, col, agg, p * 64);
    gemm_kernel<<<MPAD / 64, 512, 0, stream>>>(agg, xs, Bt, xd);
    u16* tmp = xs; xs = xd; xd = tmp;
  }
  readout_kernel<<<NN / 4, 256, 0, stream>>>(xs, W_lin, out);
}

// Round 13
// 1132.911 us; speedup vs baseline: 1.6918x; 1.0931x over previous
//
#include <hip/hip_runtime.h>
#include <hip/hip_bf16.h>

#define NN 50000
#define EE 1600000
#define FF 384
#define MPAD 50048
#define NITER 5
#define EPB 6250      // edges per block in bucket_scatter
#define BCAP 220000   // bucket capacity (mean 200000, +47 sigma)
#define GRP 6250      // rows per dst-group (NN/8)

typedef unsigned int u32;
typedef unsigned short u16;
typedef __attribute__((ext_vector_type(8))) short short8;
typedef __attribute__((ext_vector_type(4))) float f32x4;

typedef const __attribute__((address_space(1))) void* gptr_t;
typedef __attribute__((address_space(3))) void* lptr_t;

__device__ __forceinline__ float bf_lo(u32 u) {
  u32 v = u << 16;
  return __builtin_bit_cast(float, v);
}
__device__ __forceinline__ float bf_hi(u32 u) {
  u32 v = u & 0xFFFF0000u;
  return __builtin_bit_cast(float, v);
}
__device__ __forceinline__ u32 f2bf(float f) {  // RNE f32 -> bf16 bits
  u32 u = __builtin_bit_cast(u32, f);
  return (u + 0x7FFFu + ((u >> 16) & 1u)) >> 16;
}
__device__ __forceinline__ u32 pack2(float lo, float hi) {
  return f2bf(lo) | (f2bf(hi) << 16);
}
__device__ __forceinline__ void load16_lds(const void* g, void* l) {
  __builtin_amdgcn_global_load_lds((gptr_t)g, (lptr_t)l, 16, 0, 0);
}

// ---------------- setup (atomic-free CSR build) ----------------
__global__ void init_bcur_kernel(int* __restrict__ bcur) {
  if (threadIdx.x < 8) bcur[threadIdx.x] = threadIdx.x * BCAP;
}

// Pass A: block-local LDS counting sort of 6250 edges into 8 dst-range buckets,
// then fully COALESCED copy-out to reserved global bucket ranges.
__global__ __launch_bounds__(256) void bucket_scatter_kernel(
    const int* __restrict__ src, const int* __restrict__ dst,
    int* __restrict__ bcur, int* __restrict__ es_src, int* __restrict__ es_dst) {
  __shared__ int osrc[EPB];
  __shared__ int odst[EPB];
  __shared__ int h[8], lo8[8], gbase[8], c2[8];
  const int t = threadIdx.x;
  if (t < 8) { h[t] = 0; c2[t] = 0; }
  __syncthreads();
  const int e0 = blockIdx.x * EPB;
  for (int i = t; i < EPB; i += 256) {
    int d = dst[e0 + i];
    atomicAdd(&h[d / GRP], 1);
  }
  __syncthreads();
  if (t == 0) { int r = 0; for (int b = 0; b < 8; ++b) { lo8[b] = r; r += h[b]; } }
  __syncthreads();
  if (t < 8) gbase[t] = atomicAdd(&bcur[t], h[t]);
  __syncthreads();
  for (int i = t; i < EPB; i += 256) {
    int s = src[e0 + i], d = dst[e0 + i];
    int b = d / GRP;
    int p = lo8[b] + atomicAdd(&c2[b], 1);
    osrc[p] = s; odst[p] = d;
  }
  __syncthreads();
  for (int i = t; i < EPB; i += 256) {
    int b = 0;
    while (b < 7 && i >= lo8[b + 1]) ++b;
    int g = gbase[b] + (i - lo8[b]);
    es_src[g] = osrc[i];
    es_dst[g] = odst[i];
  }
}

// Partial LDS histograms: block (g,s) = (blockIdx>>5, blockIdx&31) histograms
// its 1/32 chunk of group g's edges into 25KB LDS -> coalesced writeout.
// ZERO global atomics.
__global__ __launch_bounds__(256) void hist_part_kernel(
    const int* __restrict__ es_dst, const int* __restrict__ bcur,
    int* __restrict__ part) {
  __shared__ int h[GRP];
  const int g = blockIdx.x >> 5;
  const int s = blockIdx.x & 31;
  const int lo = g * GRP;
  const int base = g * BCAP;
  const int n = bcur[g] - base;
  const int chunk = (n + 31) >> 5;
  const int i0 = s * chunk;
  int i1 = i0 + chunk; if (i1 > n) i1 = n;
  for (int i = threadIdx.x; i < GRP; i += 256) h[i] = 0;
  __syncthreads();
  for (int i = i0 + threadIdx.x; i < i1; i += 256)
    atomicAdd(&h[es_dst[base + i] - lo], 1);  // LDS atomic
  __syncthreads();
  int* po = part + (size_t)blockIdx.x * GRP;
  for (int i = threadIdx.x; i < GRP; i += 256) po[i] = h[i];
}

// Per-row prefix over the 32 subs (in place: part[s][r] := exclusive offset),
// cnt[r] := row total. Coalesced strided access.
__global__ void reduce_kernel(int* __restrict__ part, int* __restrict__ cnt) {
  int r = blockIdx.x * 256 + threadIdx.x;
  if (r >= NN) return;
  int g = r / GRP, o = r - g * GRP;
  int* p = part + (size_t)(g * 32) * GRP + o;
  int run = 0;
#pragma unroll
  for (int s = 0; s < 32; ++s) {
    int v = p[(size_t)s * GRP];
    p[(size_t)s * GRP] = run;
    run += v;
  }
  cnt[r] = run;
}

// 256 threads, each owns 196 rows; vectorized sums + shuffle scan
__global__ void scan_kernel(const int* __restrict__ cnt, int* __restrict__ row_start) {
  __shared__ int wsum[4];
  const int CH = 196;  // 255*196=49980 < 50000 <= 256*196
  int t = threadIdx.x;
  int lo = t * CH;
  int hi = lo + CH; if (hi > NN) hi = NN;  // t=255 -> [49980,50000), len 20 (%4==0)
  int s = 0;
  int n4 = (hi - lo) >> 2;
  const int4* p = (const int4*)(cnt + lo);
  for (int i = 0; i < n4; ++i) { int4 c = p[i]; s += c.x + c.y + c.z + c.w; }
  int lane = t & 63, w = t >> 6;
  int v = s;
  for (int d = 1; d < 64; d <<= 1) { int u = __shfl_up(v, d, 64); if (lane >= d) v += u; }
  if (lane == 63) wsum[w] = v;
  __syncthreads();
  int run = v - s;  // exclusive within wave
  for (int i = 0; i < w; ++i) run += wsum[i];
  int4* q1 = (int4*)(row_start + lo);
  for (int k = 0; k < n4; ++k) {
    int4 c = p[k];
    int4 o; o.x = run; o.y = run + c.x; o.z = o.y + c.y; o.w = o.z + c.z;
    run = o.w + c.w;
    q1[k] = o;
  }
  if (hi == NN && lo < NN) row_start[NN] = run;  // t=255: run == EE
}

// Final scatter: LDS cursors seeded from row_start + per-sub prefix.
// Slots disjoint across subs by construction. ZERO global atomics.
__global__ __launch_bounds__(256) void scatter4_kernel(
    const int* __restrict__ es_src, const int* __restrict__ es_dst,
    const int* __restrict__ bcur, const int* __restrict__ row_start,
    const int* __restrict__ part, int* __restrict__ col) {
  __shared__ int cur[GRP];
  const int g = blockIdx.x >> 5;
  const int s = blockIdx.x & 31;
  const int lo = g * GRP;
  const int base = g * BCAP;
  const int n = bcur[g] - base;
  const int chunk = (n + 31) >> 5;
  const int i0 = s * chunk;
  int i1 = i0 + chunk; if (i1 > n) i1 = n;
  const int* po = part + (size_t)blockIdx.x * GRP;
  for (int i = threadIdx.x; i < GRP; i += 256)
    cur[i] = row_start[lo + i] + po[i];
  __syncthreads();
  for (int i = i0 + threadIdx.x; i < i1; i += 256) {
    int d = es_dst[base + i];
    int p = atomicAdd(&cur[d - lo], 1);  // LDS atomic
    col[p] = es_src[base + i];
  }
}

// ---------------- converts ----------------
__global__ void convert_x_kernel(const float* __restrict__ xin, u16* __restrict__ xout) {
  size_t i = ((size_t)blockIdx.x * 256 + threadIdx.x) * 4;
  if (i >= (size_t)NN * FF) return;
  float4 f = *(const float4*)(xin + i);
  u32 o0 = pack2(f.x, f.y);
  u32 o1 = pack2(f.z, f.w);
  u32* q = (u32*)(xout + i);
  q[0] = o0; q[1] = o1;
}

// Bt[n][k] (384 x 768 bf16, row-major): k<384 -> W_rel[n][k], else W_root[n][k-384]
__global__ void build_bt_kernel(const float* __restrict__ Wr, const float* __restrict__ Wt,
                                u16* __restrict__ Bt) {
  int i = blockIdx.x * 256 + threadIdx.x;  // i = n*768 + k
  if (i >= FF * 2 * FF) return;
  int n = i / (2 * FF);
  int k = i - n * (2 * FF);
  float v = (k < FF) ? Wr[n * FF + k] : Wt[n * FF + (k - FF)];
  Bt[i] = (u16)f2bf(v);
}

// ---------------- SpMM: agg[dst] = sum_src x[src], feature-split x3 (best measured) ----------------
__global__ void spmm_pass_kernel(const u16* __restrict__ x, const int* __restrict__ rs,
                                 const int* __restrict__ col, u16* __restrict__ agg,
                                 const int fo) {
  int row = blockIdx.x * 4 + (threadIdx.x >> 6);
  int lane = threadIdx.x & 63;
  if (row >= NN) return;
  int j0 = rs[row], j1 = rs[row + 1];
  float alo = 0.f, ahi = 0.f;
  const u32* xw = (const u32*)x + fo + lane;
  int j = j0;
  for (; j + 8 <= j1; j += 8) {
    int s0 = col[j + 0], s1 = col[j + 1], s2 = col[j + 2], s3 = col[j + 3];
    int s4 = col[j + 4], s5 = col[j + 5], s6 = col[j + 6], s7 = col[j + 7];
    u32 u0 = xw[(size_t)s0 * 192];
    u32 u1 = xw[(size_t)s1 * 192];
    u32 u2 = xw[(size_t)s2 * 192];
    u32 u3 = xw[(size_t)s3 * 192];
    u32 u4 = xw[(size_t)s4 * 192];
    u32 u5 = xw[(size_t)s5 * 192];
    u32 u6 = xw[(size_t)s6 * 192];
    u32 u7 = xw[(size_t)s7 * 192];
    alo += bf_lo(u0) + bf_lo(u1) + bf_lo(u2) + bf_lo(u3) +
           bf_lo(u4) + bf_lo(u5) + bf_lo(u6) + bf_lo(u7);
    ahi += bf_hi(u0) + bf_hi(u1) + bf_hi(u2) + bf_hi(u3) +
           bf_hi(u4) + bf_hi(u5) + bf_hi(u6) + bf_hi(u7);
  }
  for (; j < j1; ++j) {
    u32 u = xw[(size_t)col[j] * 192];
    alo += bf_lo(u); ahi += bf_hi(u);
  }
  ((u32*)agg)[(size_t)row * 192 + fo + lane] = pack2(alo, ahi);
}

// ---------------- GEMM: Xout = relu([agg | x] @ Bt^T) ----------------
// bf16 in/out, fp32 accum. BM=64, BN=384 (full N -> A staged ONCE).
// 512 threads = 8 waves (2m x 4n), wave tile 32x96, acc[2][6] = 48 VGPR.
// A: LDS dbuf 2x8KB; B: LDS single 48KB (coalesced global_load_lds w16,
// XOR swizzle both). grid = 782 blocks, bijective XCD swizzle.
__global__ __launch_bounds__(512, 4) void gemm_kernel(
    const u16* __restrict__ Aagg, const u16* __restrict__ Ax,
    const u16* __restrict__ Bt, u16* __restrict__ Xout) {
  __shared__ __align__(16) u16 As[2][64 * 64];
  __shared__ __align__(16) u16 Bs[384 * 64];

  // bijective XCD swizzle: nwg=782, q=97, r=6
  const int orig = blockIdx.x;
  const int xcd = orig & 7, idx = orig >> 3;
  const int wg = ((xcd < 6) ? xcd * 98 : 6 * 98 + (xcd - 6) * 97) + idx;
  const int m0 = wg * 64;

  const int tid = threadIdx.x;
  const int lane = tid & 63;
  const int w = tid >> 6;        // 0..7
  const int wr = w >> 2;         // 0..1  (32-row half)
  const int wc = w & 3;          // 0..3  (96-col group)

  f32x4 acc[2][6] = {};

#define STAGE_A(KT, BUF)                                                        \
  {                                                                             \
    const u16* Asrc_ = ((KT) < 6) ? Aagg : Ax;                                  \
    const int kbA_ = (((KT) < 6) ? (KT) : (KT)-6) << 7;                         \
    const int rA_ = tid >> 3;                                                   \
    const int bcA_ = (tid & 7) << 4;                                            \
    load16_lds((const char*)Asrc_ + (size_t)(m0 + rA_) * 768 + kbA_ +           \
                   (bcA_ ^ ((rA_ & 7) << 4)),                                   \
               (char*)&As[BUF][0] + tid * 16);                                  \
  }

#define STAGE_B(KT)                                                             \
  {                                                                             \
    const int kbB_ = (KT) << 7;                                                 \
    _Pragma("unroll")                                                           \
    for (int i = 0; i < 6; ++i) {                                               \
      const int c = tid + i * 512;                                              \
      const int rB_ = c >> 3;                                                   \
      const int bcB_ = (c & 7) << 4;                                            \
      load16_lds((const char*)Bt + (size_t)rB_ * 1536 + kbB_ +                  \
                     (bcB_ ^ ((rB_ & 7) << 4)),                                 \
                 (char*)&Bs[0] + c * 16);                                       \
    }                                                                           \
  }

  STAGE_A(0, 0);
  STAGE_B(0);
  __syncthreads();

  int buf = 0;
  for (int kt = 0; kt < 12; ++kt) {
    if (kt < 11) STAGE_A(kt + 1, buf ^ 1);  // A prefetch overlaps compute
#pragma unroll
    for (int ks = 0; ks < 2; ++ks) {
      short8 af[2], bfm[6];
#pragma unroll
      for (int ni = 0; ni < 6; ++ni) {
        const int r = wc * 96 + ni * 16 + (lane & 15);
        const int bc = (ks * 64 + ((lane >> 4) << 4)) ^ ((r & 7) << 4);
        bfm[ni] = *(const short8*)((const char*)&Bs[0] + r * 128 + bc);
      }
#pragma unroll
      for (int mi = 0; mi < 2; ++mi) {
        const int r = wr * 32 + mi * 16 + (lane & 15);
        const int bc = (ks * 64 + ((lane >> 4) << 4)) ^ ((r & 7) << 4);
        af[mi] = *(const short8*)((const char*)&As[buf][0] + r * 128 + bc);
      }
#pragma unroll
      for (int mi = 0; mi < 2; ++mi)
#pragma unroll
        for (int ni = 0; ni < 6; ++ni)
          acc[mi][ni] = __builtin_amdgcn_mfma_f32_16x16x32_bf16(af[mi], bfm[ni], acc[mi][ni], 0, 0, 0);
    }
    __syncthreads();  // all waves done reading Bs + As[buf]; drains A prefetch
    if (kt < 11) {
      STAGE_B(kt + 1);
      __syncthreads();  // B(kt+1) ready (sibling block hides this drain)
    }
    buf ^= 1;
  }

  // epilogue: relu -> bf16. D layout: col = lane&15, row = (lane>>4)*4 + reg (m89-verified)
#pragma unroll
  for (int mi = 0; mi < 2; ++mi) {
#pragma unroll
    for (int r = 0; r < 4; ++r) {
      const int row = m0 + wr * 32 + mi * 16 + ((lane >> 4) << 2) + r;
      u16* orow = Xout + (size_t)row * FF + wc * 96 + (lane & 15);
#pragma unroll
      for (int ni = 0; ni < 6; ++ni) {
        float v = fmaxf(acc[mi][ni][r], 0.0f);
        orow[ni * 16] = (u16)f2bf(v);
      }
    }
  }
#undef STAGE_A
#undef STAGE_B
}

// ---------------- readout: out[n] = dot(x[n,:], W_lin) ----------------
__global__ void readout_kernel(const u16* __restrict__ x, const float* __restrict__ wl,
                               float* __restrict__ out) {
  int row = blockIdx.x * 4 + (threadIdx.x >> 6);
  int lane = threadIdx.x & 63;
  if (row >= NN) return;
  const u32* p = (const u32*)(x + (size_t)row * FF) + lane * 3;
  u32 u0 = p[0], u1 = p[1], u2 = p[2];
  const float* w = wl + lane * 6;
  float s = bf_lo(u0) * w[0] + bf_hi(u0) * w[1] +
            bf_lo(u1) * w[2] + bf_hi(u1) * w[3] +
            bf_lo(u2) * w[4] + bf_hi(u2) * w[5];
#pragma unroll
  for (int off = 32; off > 0; off >>= 1) s += __shfl_down(s, off, 64);
  if (lane == 0) out[row] = s;
}

extern "C" void kernel_launch(void* const* d_in, const int* in_sizes, int n_in,
                              void* d_out, int out_size, void* d_ws, size_t ws_size,
                              hipStream_t stream) {
  const float* x_in = (const float*)d_in[0];
  const int* ei = (const int*)d_in[1];
  const float* W_rel = (const float*)d_in[3];
  const float* W_root = (const float*)d_in[4];
  const float* W_lin = (const float*)d_in[5];
  float* out = (float*)d_out;

  char* ws = (char*)d_ws;
  int* cnt = (int*)(ws);                      // 200,000 B used (+64 spare)
  int* bcur = cnt + NN;                       // 8 ints in the spare
  int* row_start = (int*)(ws + 200064);       // 200,064 B
  int* col = (int*)(ws + 600192);             // 6,400,000 B
  u16* Bt = (u16*)(ws + 7000192);             // 589,824 B
  u16* agg = (u16*)(ws + 7590016);            // 38,436,864 B
  u16* x0 = (u16*)(ws + 46026880);            // 38,436,864 B
  u16* x1 = (u16*)(ws + 84463744);            // 38,436,864 B
  if (ws_size < (size_t)122900608) return;    // need ~117 MB
  // transient setup arrays overlay agg (dead before first spmm write):
  int* es_src = (int*)(ws + 7590016);               // 7,040,000 B
  int* es_dst = (int*)(ws + 7590016 + 7040000);     // 7,040,000 B
  int* part = (int*)(ws + 7590016 + 14080000);      // 6,400,000 B (ends @ 28.07MB < 38.4MB pad rows)

  const int* esrc = ei;
  const int* edst = ei + EE;

  // zero pad rows once per launch (GEMM reads them; pad outputs are row-local)
  hipMemsetAsync(agg + (size_t)NN * FF, 0, (size_t)(MPAD - NN) * FF * sizeof(u16), stream);
  hipMemsetAsync(x0 + (size_t)NN * FF, 0, (size_t)(MPAD - NN) * FF * sizeof(u16), stream);
  hipMemsetAsync(x1 + (size_t)NN * FF, 0, (size_t)(MPAD - NN) * FF * sizeof(u16), stream);

  init_bcur_kernel<<<1, 64, 0, stream>>>(bcur);
  bucket_scatter_kernel<<<EE / EPB, 256, 0, stream>>>(esrc, edst, bcur, es_src, es_dst);
  hist_part_kernel<<<256, 256, 0, stream>>>(es_dst, bcur, part);
  reduce_kernel<<<(NN + 255) / 256, 256, 0, stream>>>(part, cnt);
  scan_kernel<<<1, 256, 0, stream>>>(cnt, row_start);
  scatter4_kernel<<<256, 256, 0, stream>>>(es_src, es_dst, bcur, row_start, part, col);
  convert_x_kernel<<<(NN * FF / 4 + 255) / 256, 256, 0, stream>>>(x_in, x0);
  build_bt_kernel<<<(FF * 2 * FF + 255) / 256, 256, 0, stream>>>(W_rel, W_root, Bt);

  u16* xs = x0;
  u16* xd = x1;
  for (int t = 0; t < NITER; ++t) {
    for (int p = 0; p < 3; ++p)
      spmm_pass_kernel<<<NN / 4, 256, 0, stream>>>(xs, row_start, col, agg, p * 64);
    gemm_kernel<<<MPAD / 64, 512, 0, stream>>>(agg, xs, Bt, xd);
    u16* tmp = xs; xs = xd; xd = tmp;
  }
  readout_kernel<<<NN / 4, 256, 0, stream>>>(xs, W_lin, out);
}